// Round 3
// baseline (491.227 us; speedup 1.0000x reference)
//
#include <hip/hip_runtime.h>
#include <hip/hip_bf16.h>

#define N_NODES 50000
#define N_EDGES 800000
#define N_GRAPHS 512
#define DIM 256
#define LN_EPS 1e-5f

typedef __attribute__((ext_vector_type(8))) short bf16x8;
typedef __attribute__((ext_vector_type(4))) float f32x4;
typedef __attribute__((ext_vector_type(8))) ushort ushort8;

__device__ __forceinline__ float bf2f(ushort u) {
    union { float f; unsigned int i; } c;
    c.i = ((unsigned int)u) << 16;
    return c.f;
}
__device__ __forceinline__ ushort f2bf(float f) {
    union { float f; unsigned int i; } c;
    c.f = f;
    unsigned int r = (c.i + 0x7fffu + ((c.i >> 16) & 1u)) >> 16;
    return (ushort)r;
}
__device__ __forceinline__ float4 b2f4(ushort4 v) {
    return make_float4(bf2f(v.x), bf2f(v.y), bf2f(v.z), bf2f(v.w));
}

// async global -> LDS, 16B per lane. lds base must be wave-uniform; HW adds lane*16.
__device__ __forceinline__ void async16(const ushort* g, ushort* l) {
    __builtin_amdgcn_global_load_lds(
        (const __attribute__((address_space(1))) unsigned int*)g,
        (__attribute__((address_space(3))) unsigned int*)l,
        16, 0, 0);
}

// -------------------- CSR build --------------------

__global__ void k_hist(const int* __restrict__ dst, int* __restrict__ cnt) {
    int e = blockIdx.x * blockDim.x + threadIdx.x;
    if (e < N_EDGES) atomicAdd(&cnt[dst[e]], 1);
}

__global__ __launch_bounds__(256) void k_scan1(const int* __restrict__ cnt,
                                               int* __restrict__ row_ptr,
                                               int* __restrict__ bsum) {
    __shared__ int sd[256];
    int t = threadIdx.x, b = blockIdx.x;
    int base = b * 2048 + t * 8;
    int v[8];
    int tot = 0;
#pragma unroll
    for (int j = 0; j < 8; ++j) {
        int i = base + j;
        int c = (i < N_NODES) ? cnt[i] : 0;
        v[j] = tot;
        tot += c;
    }
    sd[t] = tot;
    __syncthreads();
    for (int off = 1; off < 256; off <<= 1) {
        int x = (t >= off) ? sd[t - off] : 0;
        __syncthreads();
        sd[t] += x;
        __syncthreads();
    }
    int excl = sd[t] - tot;
#pragma unroll
    for (int j = 0; j < 8; ++j) {
        int i = base + j;
        if (i < N_NODES) row_ptr[i] = excl + v[j];
    }
    if (t == 255) bsum[b] = sd[255];
}

// single wave, shuffle prefix scan over <=64 block sums
__global__ void k_scan2(int* __restrict__ bsum, int nb) {
    int l = threadIdx.x;
    int v = (l < nb) ? bsum[l] : 0;
    int s = v;
#pragma unroll
    for (int off = 1; off < 64; off <<= 1) {
        int u = __shfl_up(s, off);
        if (l >= off) s += u;
    }
    if (l < nb) bsum[l] = s - v;  // exclusive
}

// finalize row_ptr, init cursor, compute dinv (fused)
__global__ void k_scan3(const int* __restrict__ bsum, const int* __restrict__ cnt,
                        int* __restrict__ row_ptr, int* __restrict__ cursor,
                        float* __restrict__ dinv) {
    int i = blockIdx.x * blockDim.x + threadIdx.x;
    if (i < N_NODES) {
        int v = row_ptr[i] + bsum[i >> 11];
        row_ptr[i] = v;
        cursor[i] = v;
        dinv[i] = rsqrtf((float)cnt[i] + 1.0f);
    }
    if (i == 0) row_ptr[N_NODES] = N_EDGES;
}

__global__ void k_scatter(const int* __restrict__ src, const int* __restrict__ dst,
                          const float* __restrict__ dinv, int* __restrict__ cursor,
                          int* __restrict__ csr_src, float* __restrict__ csr_w) {
    int e = blockIdx.x * blockDim.x + threadIdx.x;
    if (e < N_EDGES) {
        int s = src[e], d = dst[e];
        int pos = atomicAdd(&cursor[d], 1);
        csr_src[pos] = s;
        csr_w[pos] = dinv[s] * dinv[d];
    }
}

// -------------------- weight transpose + bf16 cast: Wt[n][k] = bf16(W[k][n]) --------------------

__global__ __launch_bounds__(256) void k_wt(const float* __restrict__ W, ushort* __restrict__ Wt) {
    int t = threadIdx.x;
    int kbase = blockIdx.x * 16;
    for (int kk = 0; kk < 16; ++kk) {
        int k = kbase + kk;
        Wt[(size_t)t * DIM + k] = f2bf(W[(size_t)k * DIM + t]);
    }
}

// -------------------- fp32 -> bf16 convert --------------------

__global__ __launch_bounds__(256) void k_xcvt(const float* __restrict__ x, ushort* __restrict__ o) {
    int i = blockIdx.x * blockDim.x + threadIdx.x;
    const size_t total4 = (size_t)N_NODES * DIM / 4;
    if ((size_t)i < total4) {
        float4 v = *(const float4*)(x + (size_t)i * 4);
        ushort4 u;
        u.x = f2bf(v.x); u.y = f2bf(v.y); u.z = f2bf(v.z); u.w = f2bf(v.w);
        *(ushort4*)(o + (size_t)i * 4) = u;
    }
}

// -------------------- bf16 MFMA GEMM: H[M x 256] = A[M x 256] @ W[256 x 256] --------------------
// A bf16 row-major, Wt bf16 [n][k]. Output bf16. 4 waves, tile 128x128, BK=32.
// Linear LDS [128][32] (64B rows) + global_load_lds width-16 staging (m97 structure).

#define GBM 128
#define GBK 32

__global__ __launch_bounds__(256) void k_gemm(const ushort* __restrict__ A,
                                              const ushort* __restrict__ Wt,
                                              ushort* __restrict__ H, int M) {
    __shared__ ushort As[GBM * GBK];
    __shared__ ushort Bs[GBM * GBK];
    int t = threadIdx.x;
    int lane = t & 63;
    int w = t >> 6;
    int wm = w >> 1, wn = w & 1;
    int bm0 = blockIdx.x * GBM, bn0 = blockIdx.y * GBM;

    f32x4 acc[4][4];
#pragma unroll
    for (int m = 0; m < 4; ++m)
#pragma unroll
        for (int n = 0; n < 4; ++n) acc[m][n] = (f32x4)0.0f;

    int fr = lane & 15;
    int fq = lane >> 4;
    int lr = lane >> 2;         // row within 16-row staging chunk
    int lc = (lane & 3) * 8;    // ushort col within 32

    for (int k0 = 0; k0 < DIM; k0 += GBK) {
        // stage: wave w, chunk p covers rows p*64 + w*16 .. +15 (1KB each)
#pragma unroll
        for (int p = 0; p < 2; ++p) {
            int rb = p * 64 + w * 16;
            int ga = bm0 + rb + lr;
            if (ga > M - 1) ga = M - 1;
            async16(A + (size_t)ga * DIM + k0 + lc, &As[rb * GBK]);
            async16(Wt + (size_t)(bn0 + rb + lr) * DIM + k0 + lc, &Bs[rb * GBK]);
        }
        __syncthreads();
        bf16x8 af[4], bfv[4];
#pragma unroll
        for (int m = 0; m < 4; ++m)
            af[m] = *(const bf16x8*)&As[(wm * 64 + m * 16 + fr) * GBK + fq * 8];
#pragma unroll
        for (int n = 0; n < 4; ++n)
            bfv[n] = *(const bf16x8*)&Bs[(wn * 64 + n * 16 + fr) * GBK + fq * 8];
#pragma unroll
        for (int m = 0; m < 4; ++m)
#pragma unroll
            for (int n = 0; n < 4; ++n)
                acc[m][n] = __builtin_amdgcn_mfma_f32_16x16x32_bf16(af[m], bfv[n], acc[m][n], 0, 0, 0);
        __syncthreads();
    }
    // D row = (lane>>4)*4 + j, col = lane&15  [m89-verified]
#pragma unroll
    for (int m = 0; m < 4; ++m) {
        int row0 = bm0 + wm * 64 + m * 16 + fq * 4;
#pragma unroll
        for (int n = 0; n < 4; ++n) {
            int col = bn0 + wn * 64 + n * 16 + fr;
#pragma unroll
            for (int j = 0; j < 4; ++j) {
                int row = row0 + j;
                if (row < M) H[(size_t)row * DIM + col] = f2bf(acc[m][n][j]);
            }
        }
    }
}

// -------------------- aggregation + bias + LayerNorm + ReLU (bf16 in/out) --------------------
// 1 wave/node, 4 nodes/block, 4 cols/lane, edge loop unrolled x8 (8 gathers in flight).

__global__ __launch_bounds__(256) void k_agg_ln(const ushort* __restrict__ h,
                                                const int* __restrict__ rp,
                                                const int* __restrict__ cs,
                                                const float* __restrict__ cw,
                                                const float* __restrict__ dinv,
                                                const float* __restrict__ bias,
                                                const float* __restrict__ gamma,
                                                const float* __restrict__ beta,
                                                ushort* __restrict__ out) {
    int node = (blockIdx.x << 2) + (threadIdx.x >> 6);
    int lane = threadIdx.x & 63;
    int c0 = lane << 2;

    float di = dinv[node];
    float sw = di * di;
    float4 a[8];
    {
        ushort4 hv = *(const ushort4*)(h + (size_t)node * DIM + c0);
        float4 f = b2f4(hv);
        a[0] = make_float4(f.x * sw, f.y * sw, f.z * sw, f.w * sw);
    }
#pragma unroll
    for (int i = 1; i < 8; ++i) a[i] = make_float4(0.f, 0.f, 0.f, 0.f);

    int e0 = rp[node], e1 = rp[node + 1];
    for (int e = e0; e < e1; e += 8) {
        int ss[8];
        float ww[8];
#pragma unroll
        for (int i = 0; i < 8; ++i) {
            bool ok = (e + i) < e1;
            ss[i] = ok ? cs[e + i] : 0;
            ww[i] = ok ? cw[e + i] : 0.f;
        }
        ushort4 vv[8];
#pragma unroll
        for (int i = 0; i < 8; ++i)
            vv[i] = *(const ushort4*)(h + (size_t)ss[i] * DIM + c0);
#pragma unroll
        for (int i = 0; i < 8; ++i) {
            float4 f = b2f4(vv[i]);
            a[i].x += ww[i] * f.x;
            a[i].y += ww[i] * f.y;
            a[i].z += ww[i] * f.z;
            a[i].w += ww[i] * f.w;
        }
    }

    float4 v;
    v.x = ((a[0].x + a[1].x) + (a[2].x + a[3].x)) + ((a[4].x + a[5].x) + (a[6].x + a[7].x));
    v.y = ((a[0].y + a[1].y) + (a[2].y + a[3].y)) + ((a[4].y + a[5].y) + (a[6].y + a[7].y));
    v.z = ((a[0].z + a[1].z) + (a[2].z + a[3].z)) + ((a[4].z + a[5].z) + (a[6].z + a[7].z));
    v.w = ((a[0].w + a[1].w) + (a[2].w + a[3].w)) + ((a[4].w + a[5].w) + (a[6].w + a[7].w));
    float4 bi = *(const float4*)(bias + c0);
    v.x += bi.x; v.y += bi.y; v.z += bi.z; v.w += bi.w;

    float s1v = v.x + v.y + v.z + v.w;
    float s2v = v.x * v.x + v.y * v.y + v.z * v.z + v.w * v.w;
#pragma unroll
    for (int off = 1; off < 64; off <<= 1) {
        s1v += __shfl_xor(s1v, off);
        s2v += __shfl_xor(s2v, off);
    }
    float mu = s1v * (1.0f / DIM);
    float var = s2v * (1.0f / DIM) - mu * mu;
    float rstd = rsqrtf(var + LN_EPS);

    float4 g = *(const float4*)(gamma + c0);
    float4 be = *(const float4*)(beta + c0);
    ushort4 o;
    o.x = f2bf(fmaxf((v.x - mu) * rstd * g.x + be.x, 0.f));
    o.y = f2bf(fmaxf((v.y - mu) * rstd * g.y + be.y, 0.f));
    o.z = f2bf(fmaxf((v.z - mu) * rstd * g.z + be.z, 0.f));
    o.w = f2bf(fmaxf((v.w - mu) * rstd * g.w + be.w, 0.f));
    *(ushort4*)(out + (size_t)node * DIM + c0) = o;
}

// -------------------- pooling --------------------

__global__ void k_gbound(const int* __restrict__ batch, int* __restrict__ gstart) {
    int n = blockIdx.x * blockDim.x + threadIdx.x;
    if (n >= N_NODES) return;
    int bc = batch[n];
    int bp = (n == 0) ? -1 : batch[n - 1];
    for (int g = bp + 1; g <= bc; ++g) gstart[g] = n;
    if (n == N_NODES - 1)
        for (int g = bc + 1; g <= N_GRAPHS; ++g) gstart[g] = N_NODES;
}

__global__ __launch_bounds__(256) void k_pool(const ushort* __restrict__ x,
                                              const int* __restrict__ gstart,
                                              float* __restrict__ pooled) {
    int g = blockIdx.x, d = threadIdx.x;
    int r0 = gstart[g], r1 = gstart[g + 1];
    float s = 0.f;
    for (int r = r0; r < r1; ++r) s += bf2f(x[(size_t)r * DIM + d]);
    float c = (float)(r1 - r0);
    pooled[(size_t)g * DIM + d] = s / fmaxf(c, 1.0f);
}

// -------------------- final FC: out = relu(pooled @ fc_w^T + fc_b) --------------------
#define GB 16
__global__ __launch_bounds__(256) void k_fc(const float* __restrict__ pooled,
                                            const float* __restrict__ fcw,
                                            const float* __restrict__ fcb,
                                            float* __restrict__ out) {
    __shared__ float pl[GB][DIM];
    int j = threadIdx.x;
    int g0 = blockIdx.x * GB;
#pragma unroll
    for (int r = 0; r < GB; ++r) pl[r][j] = pooled[(size_t)(g0 + r) * DIM + j];
    __syncthreads();
    float acc[GB];
    float bj = fcb[j];
#pragma unroll
    for (int r = 0; r < GB; ++r) acc[r] = bj;
    for (int k = 0; k < DIM; ++k) {
        float w = fcw[(size_t)j * DIM + k];
#pragma unroll
        for (int r = 0; r < GB; ++r) acc[r] += pl[r][k] * w;
    }
#pragma unroll
    for (int r = 0; r < GB; ++r) out[(size_t)(g0 + r) * DIM + j] = fmaxf(acc[r], 0.0f);
}

// -------------------- launch --------------------

extern "C" void kernel_launch(void* const* d_in, const int* in_sizes, int n_in,
                              void* d_out, int out_size, void* d_ws, size_t ws_size,
                              hipStream_t stream) {
    const float* x = (const float*)d_in[0];
    const int* ei = (const int*)d_in[1];
    const int* src = ei;
    const int* dst = ei + N_EDGES;
    const int* batch = (const int*)d_in[2];
    const float* W[3] = {(const float*)d_in[3], (const float*)d_in[7], (const float*)d_in[11]};
    const float* bs[3] = {(const float*)d_in[4], (const float*)d_in[8], (const float*)d_in[12]};
    const float* gs[3] = {(const float*)d_in[5], (const float*)d_in[9], (const float*)d_in[13]};
    const float* be[3] = {(const float*)d_in[6], (const float*)d_in[10], (const float*)d_in[14]};
    const float* fcw = (const float*)d_in[15];
    const float* fcb = (const float*)d_in[16];
    float* out = (float*)d_out;

    char* p = (char*)d_ws;
    auto alloc = [&](size_t bytes) {
        char* r = p;
        p += (bytes + 255) & ~(size_t)255;
        return r;
    };
    ushort* h       = (ushort*)alloc((size_t)N_NODES * DIM * 2);
    ushort* bufA    = (ushort*)alloc((size_t)N_NODES * DIM * 2);
    ushort* bufB    = (ushort*)alloc((size_t)N_NODES * DIM * 2);
    ushort* Wt[3];
    for (int l = 0; l < 3; ++l) Wt[l] = (ushort*)alloc((size_t)DIM * DIM * 2);
    int*   cnt     = (int*)alloc((size_t)N_NODES * 4);
    int*   row_ptr = (int*)alloc((size_t)(N_NODES + 1) * 4);
    int*   cursor  = (int*)alloc((size_t)N_NODES * 4);
    float* dinv    = (float*)alloc((size_t)N_NODES * 4);
    int*   csr_src = (int*)alloc((size_t)N_EDGES * 4);
    float* csr_w   = (float*)alloc((size_t)N_EDGES * 4);
    int*   bsum    = (int*)alloc(256 * 4);
    int*   gstart  = (int*)alloc((size_t)(N_GRAPHS + 1) * 4);
    float* pooled  = (float*)alloc((size_t)N_GRAPHS * DIM * 4);

    hipMemsetAsync(cnt, 0, (size_t)N_NODES * 4, stream);

    const int TPB = 256;
    int gridE = (N_EDGES + TPB - 1) / TPB;
    int gridN = (N_NODES + TPB - 1) / TPB;
    const int NB1 = (N_NODES + 2047) / 2048;  // 25

    for (int l = 0; l < 3; ++l) k_wt<<<16, TPB, 0, stream>>>(W[l], Wt[l]);
    {
        int tot4 = N_NODES * DIM / 4;
        k_xcvt<<<(tot4 + TPB - 1) / TPB, TPB, 0, stream>>>(x, bufA);
    }

    k_hist<<<gridE, TPB, 0, stream>>>(dst, cnt);
    k_scan1<<<NB1, TPB, 0, stream>>>(cnt, row_ptr, bsum);
    k_scan2<<<1, 64, 0, stream>>>(bsum, NB1);
    k_scan3<<<gridN, TPB, 0, stream>>>(bsum, cnt, row_ptr, cursor, dinv);
    k_scatter<<<gridE, TPB, 0, stream>>>(src, dst, dinv, cursor, csr_src, csr_w);

    ushort* cur = bufA;
    ushort* nxt = bufB;
    for (int l = 0; l < 3; ++l) {
        dim3 gg((N_NODES + GBM - 1) / GBM, DIM / GBM);
        k_gemm<<<gg, TPB, 0, stream>>>(cur, Wt[l], h, N_NODES);
        k_agg_ln<<<N_NODES / 4, TPB, 0, stream>>>(h, row_ptr, csr_src, csr_w, dinv,
                                                  bs[l], gs[l], be[l], nxt);
        ushort* tmp = cur; cur = nxt; nxt = tmp;
    }

    k_gbound<<<gridN, TPB, 0, stream>>>(batch, gstart);
    k_pool<<<N_GRAPHS, TPB, 0, stream>>>(cur, gstart, pooled);
    k_fc<<<N_GRAPHS / GB, TPB, 0, stream>>>(pooled, fcw, fcb, out);
}